// Round 1
// baseline (570.851 us; speedup 1.0000x reference)
//
#include <hip/hip_runtime.h>
#include <hip/hip_bf16.h>

// ---------------------------------------------------------------------------
// GNN classifier on MI355X.
// Pipeline:
//   h0 = relu([shape_emb[x0]|color_emb[x1]] @ W_in + b_in)   -> 64-entry table
//   conv1: h1 = relu( (seg_sum(hltab[type[src]],dst)/deg) + hrtab[type] )
//          where hltab = h0tab@W1l, hrtab = h0tab@W1r + b1   (linearity)
//   conv2: h2 = relu( (seg_sum(h1[src],dst)@W2l)/deg + h1@W2r + b2 )
//   out   = (seg_sum(h2@W_out, batch))/cnt + b_out
// Aggregations are done via a per-call CSR (counting sort by dst) -> gathers,
// avoiding 76.8M fp32 atomics per conv.
// ---------------------------------------------------------------------------

__global__ void k_tab0(const float* __restrict__ se, const float* __restrict__ ce,
                       const float* __restrict__ Win, const float* __restrict__ bin,
                       float* __restrict__ h0tab) {
    int t = blockIdx.x, j = threadIdx.x;        // 64 blocks x 64 threads
    int s = t >> 3, c = t & 7;
    float acc = bin[j];
    for (int k = 0; k < 64; ++k) {
        acc += se[s * 64 + k] * Win[k * 64 + j];
        acc += ce[c * 64 + k] * Win[(64 + k) * 64 + j];
    }
    h0tab[t * 64 + j] = fmaxf(acc, 0.f);
}

__global__ void k_tab1(const float* __restrict__ h0tab, const float* __restrict__ W1l,
                       const float* __restrict__ W1r, const float* __restrict__ b1,
                       float* __restrict__ hltab, float* __restrict__ hrtab) {
    int t = blockIdx.x, j = threadIdx.x;        // 64 blocks x 64 threads
    float al = 0.f, ar = b1[j];
    for (int k = 0; k < 64; ++k) {
        float h = h0tab[t * 64 + k];
        al += h * W1l[k * 64 + j];
        ar += h * W1r[k * 64 + j];
    }
    hltab[t * 64 + j] = al;
    hrtab[t * 64 + j] = ar;
}

__global__ void k_prep(const int* __restrict__ x, const int* __restrict__ batch,
                       int* __restrict__ ntype, float* __restrict__ cnt, int n_nodes) {
    int n = blockIdx.x * 256 + threadIdx.x;
    if (n < n_nodes) {
        ntype[n] = x[2 * n] * 8 + x[2 * n + 1];
        atomicAdd(&cnt[batch[n]], 1.0f);
    }
}

__global__ void k_count(const int* __restrict__ dst, int* __restrict__ deg_i, int n_edges) {
    int e = blockIdx.x * 256 + threadIdx.x;
    if (e < n_edges) atomicAdd(&deg_i[dst[e]], 1);
}

// exclusive scan, 3-kernel two-level
__global__ void k_scan1(const int* __restrict__ deg_i, int* __restrict__ off,
                        int* __restrict__ bsum, int n) {
    __shared__ int sbuf[2][256];
    int tid = threadIdx.x;
    int i = blockIdx.x * 256 + tid;
    int d = (i < n) ? deg_i[i] : 0;
    int cur = 0;
    sbuf[0][tid] = d;
    __syncthreads();
    for (int ofs = 1; ofs < 256; ofs <<= 1) {
        int v = sbuf[cur][tid];
        if (tid >= ofs) v += sbuf[cur][tid - ofs];
        sbuf[cur ^ 1][tid] = v;
        cur ^= 1;
        __syncthreads();
    }
    if (i < n) off[i] = sbuf[cur][tid] - d;
    if (tid == 255) bsum[blockIdx.x] = sbuf[cur][tid];
}

__global__ void k_scan2(const int* __restrict__ bsum, int* __restrict__ bofs, int nb) {
    __shared__ int sbuf[2][512];
    int tid = threadIdx.x;
    int d = (tid < nb) ? bsum[tid] : 0;
    int cur = 0;
    sbuf[0][tid] = d;
    __syncthreads();
    for (int ofs = 1; ofs < 512; ofs <<= 1) {
        int v = sbuf[cur][tid];
        if (tid >= ofs) v += sbuf[cur][tid - ofs];
        sbuf[cur ^ 1][tid] = v;
        cur ^= 1;
        __syncthreads();
    }
    if (tid < nb) bofs[tid] = sbuf[cur][tid] - d;
}

__global__ void k_scan3(int* __restrict__ off, int* __restrict__ cursor,
                        const int* __restrict__ bofs, const int* __restrict__ deg_i,
                        float* __restrict__ inv, int n) {
    int i = blockIdx.x * 256 + threadIdx.x;
    if (i < n) {
        int o = off[i] + bofs[blockIdx.x];
        off[i] = o;
        cursor[i] = o;
        inv[i] = 1.0f / fmaxf((float)deg_i[i], 1.0f);
    }
}

__global__ void k_fill(const int* __restrict__ src, const int* __restrict__ dst,
                       int* __restrict__ cursor, int* __restrict__ csr, int n_edges) {
    int e = blockIdx.x * 256 + threadIdx.x;
    if (e < n_edges) {
        int pos = atomicAdd(&cursor[dst[e]], 1);
        csr[pos] = src[e];
    }
}

// conv1: wave per node, lane = feature dim. Table rows come from LDS.
__global__ __launch_bounds__(256) void k_gather1(
    const int* __restrict__ csr, const int* __restrict__ off,
    const int* __restrict__ deg_i, const float* __restrict__ inv,
    const int* __restrict__ ntype, const float* __restrict__ hltab,
    const float* __restrict__ hrtab, float* __restrict__ h1, int n_nodes) {
    __shared__ float tl[4096];
    __shared__ float tr_[4096];
    for (int i = threadIdx.x; i < 4096; i += 256) { tl[i] = hltab[i]; tr_[i] = hrtab[i]; }
    __syncthreads();
    int lane = threadIdx.x & 63;
    int wslot = blockIdx.x * 4 + (threadIdx.x >> 6);
    int nwaves = gridDim.x * 4;
    for (int n = wslot; n < n_nodes; n += nwaves) {
        int o = off[n], d = deg_i[n];
        float acc = 0.f;
        int i = 0;
        for (; i + 1 < d; i += 2) {         // ILP-2 to overlap the load chains
            int s0 = csr[o + i], s1 = csr[o + i + 1];
            int t0 = ntype[s0], t1 = ntype[s1];
            acc += tl[t0 * 64 + lane] + tl[t1 * 64 + lane];
        }
        if (i < d) acc += tl[ntype[csr[o + i]] * 64 + lane];
        h1[(size_t)n * 64 + lane] = fmaxf(acc * inv[n] + tr_[ntype[n] * 64 + lane], 0.f);
    }
}

// conv2 aggregation: wave per node, gather h1 rows of in-neighbors.
__global__ __launch_bounds__(256) void k_gather2(
    const int* __restrict__ csr, const int* __restrict__ off,
    const int* __restrict__ deg_i, const float* __restrict__ h1,
    float* __restrict__ agg2, int n_nodes) {
    int lane = threadIdx.x & 63;
    int wslot = blockIdx.x * 4 + (threadIdx.x >> 6);
    int nwaves = gridDim.x * 4;
    for (int n = wslot; n < n_nodes; n += nwaves) {
        int o = off[n], d = deg_i[n];
        float acc = 0.f;
        int i = 0;
        for (; i + 1 < d; i += 2) {
            int s0 = csr[o + i], s1 = csr[o + i + 1];
            acc += h1[(size_t)s0 * 64 + lane] + h1[(size_t)s1 * 64 + lane];
        }
        if (i < d) acc += h1[(size_t)csr[o + i] * 64 + lane];
        agg2[(size_t)n * 64 + lane] = acc;
    }
}

// conv2 GEMMs + relu + W_out projection + pooled accumulation.
// Block: 256 threads, 64 nodes. Thread: 4 nodes x 4 dims, k-loop 64.
__global__ __launch_bounds__(256) void k_finish2(
    const float* __restrict__ agg2, const float* __restrict__ h1,
    const float* __restrict__ inv, const int* __restrict__ batch,
    const float* __restrict__ W2l, const float* __restrict__ W2r,
    const float* __restrict__ b2, const float* __restrict__ Wout,
    float* __restrict__ outacc, int n_nodes) {
    __shared__ float sWl[4096];
    __shared__ float sWr[4096];
    __shared__ float sb2[64];
    __shared__ float sWo[128];
    int tid = threadIdx.x;
    for (int i = tid; i < 4096; i += 256) { sWl[i] = W2l[i]; sWr[i] = W2r[i]; }
    if (tid < 64) sb2[tid] = b2[tid];
    if (tid < 128) sWo[tid] = Wout[tid];
    __syncthreads();

    int n0 = blockIdx.x * 64;
    int tr = tid >> 4, tc = tid & 15;
    int r0 = tr * 4, c0 = tc * 4;

    int gn[4], gc[4];
    float iv[4];
#pragma unroll
    for (int i = 0; i < 4; ++i) {
        gn[i] = n0 + r0 + i;
        gc[i] = gn[i] < n_nodes ? gn[i] : (n_nodes - 1);   // clamp for safe loads
        iv[i] = inv[gc[i]];
    }

    float accl[4][4] = {{0.f}}, accr[4][4] = {{0.f}};
    for (int k = 0; k < 64; k += 4) {
        float4 av[4], hv[4];
#pragma unroll
        for (int i = 0; i < 4; ++i) {
            av[i] = *(const float4*)(agg2 + (size_t)gc[i] * 64 + k);
            hv[i] = *(const float4*)(h1 + (size_t)gc[i] * 64 + k);
        }
#pragma unroll
        for (int kk = 0; kk < 4; ++kk) {
            float4 wl = *(const float4*)(sWl + (k + kk) * 64 + c0);
            float4 wr = *(const float4*)(sWr + (k + kk) * 64 + c0);
#pragma unroll
            for (int i = 0; i < 4; ++i) {
                float a = (&av[i].x)[kk];
                float h = (&hv[i].x)[kk];
                accl[i][0] += a * wl.x; accr[i][0] += h * wr.x;
                accl[i][1] += a * wl.y; accr[i][1] += h * wr.y;
                accl[i][2] += a * wl.z; accr[i][2] += h * wr.z;
                accl[i][3] += a * wl.w; accr[i][3] += h * wr.w;
            }
        }
    }

    // h2 = relu(accl*inv + accr + b2); project to 2 classes; reduce over 16 tc lanes
    float p0[4], p1[4];
#pragma unroll
    for (int i = 0; i < 4; ++i) {
        p0[i] = 0.f; p1[i] = 0.f;
#pragma unroll
        for (int j = 0; j < 4; ++j) {
            float v = fmaxf(accl[i][j] * iv[i] + accr[i][j] + sb2[c0 + j], 0.f);
            p0[i] += v * sWo[(c0 + j) * 2 + 0];
            p1[i] += v * sWo[(c0 + j) * 2 + 1];
        }
    }
#pragma unroll
    for (int m = 1; m < 16; m <<= 1) {
#pragma unroll
        for (int i = 0; i < 4; ++i) {
            p0[i] += __shfl_xor(p0[i], m);
            p1[i] += __shfl_xor(p1[i], m);
        }
    }
    if (tc == 0) {
#pragma unroll
        for (int i = 0; i < 4; ++i) {
            if (gn[i] < n_nodes) {
                int g = batch[gn[i]];
                atomicAdd(&outacc[g * 2 + 0], p0[i]);
                atomicAdd(&outacc[g * 2 + 1], p1[i]);
            }
        }
    }
}

__global__ void k_out(const float* __restrict__ outacc, const float* __restrict__ cnt,
                      const float* __restrict__ bout, float* __restrict__ out, int n_graphs) {
    int i = blockIdx.x * 256 + threadIdx.x;
    if (i < n_graphs * 2) {
        int g = i >> 1, c = i & 1;
        out[i] = outacc[i] / fmaxf(cnt[g], 1.0f) + bout[c];
    }
}

extern "C" void kernel_launch(void* const* d_in, const int* in_sizes, int n_in,
                              void* d_out, int out_size, void* d_ws, size_t ws_size,
                              hipStream_t stream) {
    const int* x     = (const int*)d_in[0];
    const int* ei    = (const int*)d_in[1];
    const int* batch = (const int*)d_in[2];
    // d_in[3] = num_graphs (device scalar) -- derived from out_size instead
    const float* se   = (const float*)d_in[4];
    const float* ce   = (const float*)d_in[5];
    const float* Win  = (const float*)d_in[6];
    const float* bin  = (const float*)d_in[7];
    const float* W1l  = (const float*)d_in[8];
    const float* b1   = (const float*)d_in[9];
    const float* W1r  = (const float*)d_in[10];
    const float* W2l  = (const float*)d_in[11];
    const float* b2   = (const float*)d_in[12];
    const float* W2r  = (const float*)d_in[13];
    const float* Wout = (const float*)d_in[14];
    const float* bout = (const float*)d_in[15];
    float* out = (float*)d_out;

    int n_nodes  = in_sizes[0] / 2;
    int n_edges  = in_sizes[1] / 2;
    int n_graphs = out_size / 2;
    const int* src = ei;
    const int* dst = ei + n_edges;

    char* p = (char*)d_ws;
    auto take = [&](size_t bytes) { char* r = p; p += (bytes + 255) & ~(size_t)255; return r; };
    float* h1     = (float*)take((size_t)n_nodes * 64 * 4);
    float* agg2   = (float*)take((size_t)n_nodes * 64 * 4);
    int*   csr    = (int*)take((size_t)n_edges * 4);
    int*   ntype  = (int*)take((size_t)n_nodes * 4);
    int*   deg_i  = (int*)take((size_t)n_nodes * 4);
    int*   off    = (int*)take((size_t)n_nodes * 4);
    int*   cursor = (int*)take((size_t)n_nodes * 4);
    float* inv    = (float*)take((size_t)n_nodes * 4);
    int*   bsum   = (int*)take(512 * 4);
    int*   bofs   = (int*)take(512 * 4);
    float* cnt    = (float*)take((size_t)n_graphs * 4);
    float* outacc = (float*)take((size_t)n_graphs * 8);
    float* h0tab  = (float*)take(4096 * 4);
    float* hltab  = (float*)take(4096 * 4);
    float* hrtab  = (float*)take(4096 * 4);

    int nbN = (n_nodes + 255) / 256;
    int nbE = (n_edges + 255) / 256;

    hipMemsetAsync(deg_i, 0, (size_t)n_nodes * 4, stream);
    hipMemsetAsync(cnt, 0, (size_t)n_graphs * 4, stream);
    hipMemsetAsync(outacc, 0, (size_t)n_graphs * 8, stream);

    k_tab0<<<64, 64, 0, stream>>>(se, ce, Win, bin, h0tab);
    k_tab1<<<64, 64, 0, stream>>>(h0tab, W1l, W1r, b1, hltab, hrtab);
    k_prep<<<nbN, 256, 0, stream>>>(x, batch, ntype, cnt, n_nodes);
    k_count<<<nbE, 256, 0, stream>>>(dst, deg_i, n_edges);
    k_scan1<<<nbN, 256, 0, stream>>>(deg_i, off, bsum, n_nodes);
    k_scan2<<<1, 512, 0, stream>>>(bsum, bofs, nbN);
    k_scan3<<<nbN, 256, 0, stream>>>(off, cursor, bofs, deg_i, inv, n_nodes);
    k_fill<<<nbE, 256, 0, stream>>>(src, dst, cursor, csr, n_edges);
    k_gather1<<<2048, 256, 0, stream>>>(csr, off, deg_i, inv, ntype, hltab, hrtab, h1, n_nodes);
    k_gather2<<<2048, 256, 0, stream>>>(csr, off, deg_i, h1, agg2, n_nodes);
    k_finish2<<<(n_nodes + 63) / 64, 256, 0, stream>>>(agg2, h1, inv, batch, W2l, W2r, b2,
                                                       Wout, outacc, n_nodes);
    k_out<<<(n_graphs * 2 + 255) / 256, 256, 0, stream>>>(outacc, cnt, bout, out, n_graphs);
}